// Round 6
// baseline (288.916 us; speedup 1.0000x reference)
//
#include <hip/hip_runtime.h>
#include <math.h>

// Problem constants
#define BROWS 16384
#define N0    2048
#define NCLS  12
#define NCLU  24
#define NDIM  4
#define NCOL  348          // 12 + 288 + 48
#define NPAD  384          // padded fused-column count (24 col-tiles of 16)
#define NTILE 24           // NPAD/16

// Output offsets (floats): y0 [B,12] | y1_sel [B,24] | y2_sel [B,4] | Plc [B,24,12]
#define OUT0_OFF 0
#define OUT1_OFF (BROWS * NCLS)
#define OUT2_OFF (OUT1_OFF + BROWS * NCLU)
#define OUT3_OFF (OUT2_OFF + BROWS * NDIM)

typedef __attribute__((ext_vector_type(8))) short bf16x8;
typedef __attribute__((ext_vector_type(4))) float f32x4;
typedef unsigned short ushort_t;

// ---------------------------------------------------------------------------
// bf16 helpers — RNE split (bit-identical to the passing numerics)
// ---------------------------------------------------------------------------
__device__ __forceinline__ unsigned short f2bf(float f) {   // RNE
    unsigned u = __float_as_uint(f);
    u += 0x7fffu + ((u >> 16) & 1u);
    return (unsigned short)(u >> 16);
}
__device__ __forceinline__ float bf2f(unsigned short h) {
    return __uint_as_float(((unsigned)h) << 16);
}

// Packed-HW cvt: v_cvt_pk_bf16_f32 is RNE — bit-identical to the integer
// split, ~3x fewer VALU ops. No builtin on gfx950 -> inline asm.
__device__ __forceinline__ void cvt8pk(float4 a, float4 b, bf16x8& h, bf16x8& l) {
    unsigned h0, h1, h2, h3;
    asm("v_cvt_pk_bf16_f32 %0, %1, %2" : "=v"(h0) : "v"(a.x), "v"(a.y));
    asm("v_cvt_pk_bf16_f32 %0, %1, %2" : "=v"(h1) : "v"(a.z), "v"(a.w));
    asm("v_cvt_pk_bf16_f32 %0, %1, %2" : "=v"(h2) : "v"(b.x), "v"(b.y));
    asm("v_cvt_pk_bf16_f32 %0, %1, %2" : "=v"(h3) : "v"(b.z), "v"(b.w));
    // lo-plane residuals: exact fp32 subtraction of the hi bf16 value
    float r0 = a.x - __uint_as_float(h0 << 16);
    float r1 = a.y - __uint_as_float(h0 & 0xffff0000u);
    float r2 = a.z - __uint_as_float(h1 << 16);
    float r3 = a.w - __uint_as_float(h1 & 0xffff0000u);
    float r4 = b.x - __uint_as_float(h2 << 16);
    float r5 = b.y - __uint_as_float(h2 & 0xffff0000u);
    float r6 = b.z - __uint_as_float(h3 << 16);
    float r7 = b.w - __uint_as_float(h3 & 0xffff0000u);
    unsigned l0, l1, l2, l3;
    asm("v_cvt_pk_bf16_f32 %0, %1, %2" : "=v"(l0) : "v"(r0), "v"(r1));
    asm("v_cvt_pk_bf16_f32 %0, %1, %2" : "=v"(l1) : "v"(r2), "v"(r3));
    asm("v_cvt_pk_bf16_f32 %0, %1, %2" : "=v"(l2) : "v"(r4), "v"(r5));
    asm("v_cvt_pk_bf16_f32 %0, %1, %2" : "=v"(l3) : "v"(r6), "v"(r7));
    union Pack { unsigned u[4]; bf16x8 v; };
    Pack H; H.u[0] = h0; H.u[1] = h1; H.u[2] = h2; H.u[3] = h3;
    Pack L; L.u[0] = l0; L.u[1] = l1; L.u[2] = l2; L.u[3] = l3;
    h = H.v;
    l = L.v;
}

__device__ __forceinline__ void load_lds16(const void* g, void* l) {
    __builtin_amdgcn_global_load_lds((const __attribute__((address_space(1))) void*)g,
                                     (__attribute__((address_space(3))) void*)l, 16, 0, 0);
}

__device__ __forceinline__ float fused_w(const float* __restrict__ W_fc,
                                         const float* __restrict__ W_bin,
                                         const float* __restrict__ W_res,
                                         int col, int d) {
    float w = 0.0f;
    if (col < NCLS) {
        w = W_fc[d * NCLS + col];
    } else if (col < 12 + NCLU * NCLS) {
        int jj = col - 12;
        int k = jj / NCLS, c = jj - k * NCLS;
        w = W_bin[((size_t)c * N0 + d) * NCLU + k];
    } else if (col < NCOL) {
        int jj = col - 300;
        int n = jj / NCLS, c = jj - n * NCLS;
        w = W_res[((size_t)c * N0 + d) * NDIM + n];
    }
    return w;
}

// ---------------------------------------------------------------------------
// Kernel 1: repack fused weights straight into MFMA-fragment streaming order.
//   Bp{h,l}[((J*64 + kb)*64 + lane)*8 + i] = W[col = J*16 + (lane&15)]
//                                             [k  = kb*32 + (lane>>4)*8 + i]
// ---------------------------------------------------------------------------
__global__ void jcp_repack3(const float* __restrict__ W_fc, const float* __restrict__ b_fc,
                            const float* __restrict__ W_bin, const float* __restrict__ b_bin,
                            const float* __restrict__ W_res, const float* __restrict__ b_res,
                            ushort_t* __restrict__ Bph, ushort_t* __restrict__ Bpl,
                            float* __restrict__ bias) {
    int t = blockIdx.x * 256 + threadIdx.x;          // 0 .. 98303
    if (t >= NTILE * 64 * 64) return;
    const int lane = t & 63;
    const int kb   = (t >> 6) & 63;
    const int J    = t >> 12;
    const int col  = J * 16 + (lane & 15);
    const int k0   = kb * 32 + (lane >> 4) * 8;

    bf16x8 h, l;
    #pragma unroll
    for (int i = 0; i < 8; ++i) {
        float w = fused_w(W_fc, W_bin, W_res, col, k0 + i);
        unsigned short hi = f2bf(w);
        h[i] = (short)hi;
        l[i] = (short)f2bf(w - bf2f(hi));
    }
    *(bf16x8*)(Bph + (size_t)t * 8) = h;
    *(bf16x8*)(Bpl + (size_t)t * 8) = l;

    if (t < NPAD) {
        int jb = t;
        float bv = 0.0f;
        if (jb < NCLS) {
            bv = b_fc[jb];
        } else if (jb < 12 + NCLU * NCLS) {
            int jj = jb - 12;
            int k = jj / NCLS, c = jj - k * NCLS;
            bv = b_bin[c * NCLU + k];
        } else if (jb < NCOL) {
            int jj = jb - 300;
            int n = jj / NCLS, c = jj - n * NCLS;
            bv = b_res[c * NDIM + n];
        }
        bias[jb] = bv;
    }
}

// ---------------------------------------------------------------------------
// Kernel 2: split-bf16 MFMA GEMM v10 — gemm9 pipeline, occupancy-doubled.
//   Block tile 64x96 (4 waves, wave = 32x48, acc[2][3], 18 MFMA/iter).
//   LDS 40 KB (x dbuf 2x8KB + B dbuf 2x12KB) -> 4 blocks/CU (160 KB exact),
//   grid 1024 = 256 row-panels x 4 col-blocks = exactly 4 blocks/CU, no tail.
//   4 independent blocks per CU at different pipeline phases overlap the
//   MFMA / VALU(cvt) / LDS / DMA pipes that ran serially at 2 blocks/CU.
//   Pipeline: counted s_waitcnt vmcnt(5) (= 5 DMAs/wave/buffer: 2 x + 3 B),
//   raw s_barrier pair, refill for it+2, setprio around the MFMA cluster.
// ---------------------------------------------------------------------------
__global__ __launch_bounds__(256, 4) void jcp_gemm10(const float* __restrict__ x,
                                                     const ushort_t* __restrict__ Bph,
                                                     const ushort_t* __restrict__ Bpl,
                                                     const float* __restrict__ bias,
                                                     float* __restrict__ Y) {
    __shared__ float    Lx[2 * 2048];    // 2 bufs x 64 rows x 32 fp32 = 8 KB each
    __shared__ ushort_t Lb[2 * 6144];    // 2 bufs x 12 chunks x 512 ushorts = 12 KB each

    const int tid  = threadIdx.x;
    const int wid  = tid >> 6;
    const int lane = tid & 63;
    const int quad = lane >> 4;
    const int l16  = lane & 15;
    const int rg   = wid & 1;            // 32-row half of block
    const int cg   = wid >> 1;           // 48-col half of block

    // XCD-bijective decode: 4 col-blocks of a row-panel land on one XCD.
    const int g   = blockIdx.x;          // 0..1023, 1024 % 8 == 0 -> bijective
    const int xcd = g & 7;
    const int jj  = g >> 3;              // 0..127
    const int by  = xcd * 32 + (jj >> 2);   // 0..255
    const int bx  = jj & 3;
    const int rbase = by * 64;
    const int jbase = bx * 96;

    // --- x DMA (raw fp32): 2 insts/thread; inst n covers rows n*32 + (tid>>3),
    //     dest chunk tid&7 (16B units), source chunk XOR-swizzled by row. ---
    const int r0 = tid >> 3;             // 0..31
    const int c0 = tid & 7;
    const int o0 = c0 ^ (r0 & 7);        // (r0+32n)&7 == r0&7
    const float* gx = x + (size_t)(rbase + r0) * N0 + o0 * 4;   // + it*32 ; inst n: +n*65536
    // dest float offset: n*1024 + tid*4

    // --- B DMA: 3 insts/thread; wave w stages chunks w, 4+w, 8+w (1 KB each).
    const ushort_t* gb[3];
    int bdst[3];
    #pragma unroll
    for (int m = 0; m < 3; ++m) {
        const int c  = m * 4 + wid;                  // 0..11, wave-uniform
        const int J  = bx * 6 + (c >> 1);            // global col-tile 0..23
        const ushort_t* bp = (c & 1) ? Bpl : Bph;
        gb[m]   = bp + (size_t)J * 32768 + lane * 8; // + it*512 per iter
        bdst[m] = c * 512 + lane * 8;
    }

    // --- A fragment read offsets (floats), proven swizzled layout ---
    const int s  = l16 & 7;
    const int o1 = ((2 * quad) ^ s) * 4;
    const int o2 = o1 ^ 4;

    f32x4 acc[2][3];
    #pragma unroll
    for (int rt = 0; rt < 2; ++rt)
        #pragma unroll
        for (int j = 0; j < 3; ++j)
            acc[rt][j] = f32x4{0.f, 0.f, 0.f, 0.f};

    // Prologue: issue buf0's 5 DMAs/wave (it=0), then buf1's 5 (it=1).
    #pragma unroll
    for (int n = 0; n < 2; ++n) load_lds16(gx + n * 65536, &Lx[n * 1024 + tid * 4]);
    #pragma unroll
    for (int m = 0; m < 3; ++m) load_lds16(gb[m], &Lb[bdst[m]]);
    #pragma unroll
    for (int n = 0; n < 2; ++n) load_lds16(gx + n * 65536 + 32, &Lx[2048 + n * 1024 + tid * 4]);
    #pragma unroll
    for (int m = 0; m < 3; ++m) load_lds16(gb[m] + 512, &Lb[6144 + bdst[m]]);

    int p = 0;
    for (int it = 0; it < 63; ++it) {
        // Drain only this buffer's 5 loads; next buffer's 5 stay in flight.
        asm volatile("s_waitcnt vmcnt(5)" ::: "memory");
        asm volatile("s_barrier" ::: "memory");          // buf p ready (all waves)

        const float*    lx = &Lx[p * 2048];
        const ushort_t* lb = &Lb[p * 6144];

        // A fragments: fp32 float4 pairs from swizzled LDS.
        float4 fa[2], fb[2];
        #pragma unroll
        for (int rt = 0; rt < 2; ++rt) {
            const int ro = (rg * 32 + rt * 16 + l16) * 32;
            fa[rt] = *(const float4*)&lx[ro + o1];
            fb[rt] = *(const float4*)&lx[ro + o2];
        }
        // B fragments: 6 x ds_read_b128 (3 col-tiles x hi/lo)
        bf16x8 bh[3], bl[3];
        #pragma unroll
        for (int j = 0; j < 3; ++j) {
            const int ch = (cg * 3 + j) * 2;
            bh[j] = *(const bf16x8*)(lb + ch * 512 + lane * 8);
            bl[j] = *(const bf16x8*)(lb + ch * 512 + 512 + lane * 8);
        }
        asm volatile("s_waitcnt lgkmcnt(0)" ::: "memory");   // frags in regs
        asm volatile("s_barrier" ::: "memory");              // all waves done reading p

        // Refill buf p for iteration it+2 (lands while we MFMA + next iter runs).
        if (it < 62) {
            #pragma unroll
            for (int n = 0; n < 2; ++n)
                load_lds16(gx + n * 65536 + (it + 2) * 32,
                           &Lx[p * 2048 + n * 1024 + tid * 4]);
            #pragma unroll
            for (int m = 0; m < 3; ++m)
                load_lds16(gb[m] + (it + 2) * 512, &Lb[p * 6144 + bdst[m]]);
        }

        // Convert A fragments (packed HW cvt, bit-identical) — overlaps DMA issue.
        bf16x8 Ah[2], Al[2];
        #pragma unroll
        for (int rt = 0; rt < 2; ++rt) cvt8pk(fa[rt], fb[rt], Ah[rt], Al[rt]);

        // 18 MFMAs: per-accumulator order hh -> lh -> hl (bit-identical)
        __builtin_amdgcn_s_setprio(1);
        #pragma unroll
        for (int j = 0; j < 3; ++j)
            #pragma unroll
            for (int rt = 0; rt < 2; ++rt) {
                acc[rt][j] = __builtin_amdgcn_mfma_f32_16x16x32_bf16(Ah[rt], bh[j], acc[rt][j], 0, 0, 0);
                acc[rt][j] = __builtin_amdgcn_mfma_f32_16x16x32_bf16(Al[rt], bh[j], acc[rt][j], 0, 0, 0);
                acc[rt][j] = __builtin_amdgcn_mfma_f32_16x16x32_bf16(Ah[rt], bl[j], acc[rt][j], 0, 0, 0);
            }
        __builtin_amdgcn_s_setprio(0);
        p ^= 1;
    }

    // Peeled last iteration (buf p): only its 5 loads remain.
    {
        asm volatile("s_waitcnt vmcnt(0)" ::: "memory");
        asm volatile("s_barrier" ::: "memory");
        const float*    lx = &Lx[p * 2048];
        const ushort_t* lb = &Lb[p * 6144];
        bf16x8 Ah[2], Al[2];
        #pragma unroll
        for (int rt = 0; rt < 2; ++rt) {
            const int ro = (rg * 32 + rt * 16 + l16) * 32;
            float4 fa = *(const float4*)&lx[ro + o1];
            float4 fb = *(const float4*)&lx[ro + o2];
            cvt8pk(fa, fb, Ah[rt], Al[rt]);
        }
        bf16x8 bh[3], bl[3];
        #pragma unroll
        for (int j = 0; j < 3; ++j) {
            const int ch = (cg * 3 + j) * 2;
            bh[j] = *(const bf16x8*)(lb + ch * 512 + lane * 8);
            bl[j] = *(const bf16x8*)(lb + ch * 512 + 512 + lane * 8);
        }
        #pragma unroll
        for (int j = 0; j < 3; ++j)
            #pragma unroll
            for (int rt = 0; rt < 2; ++rt) {
                acc[rt][j] = __builtin_amdgcn_mfma_f32_16x16x32_bf16(Ah[rt], bh[j], acc[rt][j], 0, 0, 0);
                acc[rt][j] = __builtin_amdgcn_mfma_f32_16x16x32_bf16(Al[rt], bh[j], acc[rt][j], 0, 0, 0);
                acc[rt][j] = __builtin_amdgcn_mfma_f32_16x16x32_bf16(Ah[rt], bl[j], acc[rt][j], 0, 0, 0);
            }
    }

    // Epilogue: C/D layout col = lane&15, row = quad*4 + reg
    #pragma unroll
    for (int j = 0; j < 3; ++j) {
        const int col = jbase + cg * 48 + 16 * j + l16;
        const float bj = bias[col];
        #pragma unroll
        for (int rt = 0; rt < 2; ++rt) {
            float* yp = Y + (size_t)(rbase + rg * 32 + rt * 16 + quad * 4) * NPAD + col;
            yp[0 * NPAD] = acc[rt][j][0] + bj;
            yp[1 * NPAD] = acc[rt][j][1] + bj;
            yp[2 * NPAD] = acc[rt][j][2] + bj;
            yp[3 * NPAD] = acc[rt][j][3] + bj;
        }
    }
}

// ---------------------------------------------------------------------------
// Kernel 3: head v4. Block = 256 thr = 16 rows x 16 lanes (lane = class).
// ---------------------------------------------------------------------------
#define LROW 388   // padded LDS row stride (floats)

__global__ __launch_bounds__(256) void jcp_head4(const float* __restrict__ Y,
                                                 float* __restrict__ out) {
    __shared__ float Ly[16 * LROW];
    const int tid = threadIdx.x;
    const int r0  = blockIdx.x * 16;

    #pragma unroll
    for (int jj = 0; jj < 6; ++jj) {
        int f = tid + jj * 256;
        int row = f / 96, c4 = f - row * 96;
        float4 v = *(const float4*)(Y + (size_t)(r0 + row) * NPAD + c4 * 4);
        *(float4*)&Ly[row * LROW + c4 * 4] = v;
    }
    __syncthreads();

    const int grp = tid >> 4;
    const int c   = tid & 15;
    const bool on = (c < NCLS);
    const int r   = r0 + grp;
    const float* y = &Ly[grp * LROW];

    float y0c = on ? y[c] : -INFINITY;
    float m0 = y0c;
    #pragma unroll
    for (int m = 8; m >= 1; m >>= 1) m0 = fmaxf(m0, __shfl_xor(m0, m, 16));
    float e0 = on ? expf(y0c - m0) : 0.0f;
    float s0 = e0;
    #pragma unroll
    for (int m = 8; m >= 1; m >>= 1) s0 += __shfl_xor(s0, m, 16);
    const float Pc = e0 / s0;

    float v[NCLU];
    float mc = -INFINITY;
    #pragma unroll
    for (int k = 0; k < NCLU; ++k) {
        v[k] = y[12 + k * NCLS + c];
        mc = fmaxf(mc, v[k]);
    }
    float ev[NCLU];
    float sc = 0.0f;
    #pragma unroll
    for (int k = 0; k < NCLU; ++k) { ev[k] = expf(v[k] - mc); sc += ev[k]; }
    const float rs = Pc / sc;

    float y2c[NDIM];
    #pragma unroll
    for (int n = 0; n < NDIM; ++n) y2c[n] = y[300 + n * NCLS + c];

    float best = -INFINITY;
    int bk = 0;
    float* lrow = &Ly[grp * LROW];
    #pragma unroll
    for (int k = 0; k < NCLU; ++k) {
        const float p = ev[k] * rs;
        if (on) lrow[k * NCLS + c] = p;
        if (p > best) { best = p; bk = k; }
    }
    int flat = bk * NCLS + c;
    if (!on) { best = -INFINITY; flat = 1 << 30; }

    #pragma unroll
    for (int m = 8; m >= 1; m >>= 1) {
        const float op = __shfl_xor(best, m, 16);
        const int   of = __shfl_xor(flat, m, 16);
        if (op > best || (op == best && of < flat)) { best = op; flat = of; }
    }
    const int ic = flat % NCLS;

    if (on) out[OUT0_OFF + (size_t)r * NCLS + c] = y0c;
    if (c == ic) {
        float* o1 = out + OUT1_OFF + (size_t)r * NCLU;
        #pragma unroll
        for (int k = 0; k < NCLU; ++k) o1[k] = v[k];
        float* o2 = out + OUT2_OFF + (size_t)r * NDIM;
        #pragma unroll
        for (int n = 0; n < NDIM; ++n) o2[n] = y2c[n];
    }

    __syncthreads();
    #pragma unroll
    for (int jj = 0; jj < 5; ++jj) {
        int f = tid + jj * 256;
        if (f < 1152) {
            int row = f / 72, c4 = f - row * 72;
            *(float4*)(out + OUT3_OFF + (size_t)(r0 + row) * (NCLU * NCLS) + c4 * 4) =
                *(float4*)&Ly[row * LROW + c4 * 4];
        }
    }
}

// ---------------------------------------------------------------------------
extern "C" void kernel_launch(void* const* d_in, const int* in_sizes, int n_in,
                              void* d_out, int out_size, void* d_ws, size_t ws_size,
                              hipStream_t stream) {
    const float* x     = (const float*)d_in[0];
    const float* W_fc  = (const float*)d_in[1];
    const float* b_fc  = (const float*)d_in[2];
    const float* W_bin = (const float*)d_in[3];
    const float* b_bin = (const float*)d_in[4];
    const float* W_res = (const float*)d_in[5];
    const float* b_res = (const float*)d_in[6];
    float* out = (float*)d_out;

    // ws layout (bytes): Bph 1.5MB | Bpl 1.5MB | bias 1.5KB | Y 25.2MB
    ushort_t* Bph  = (ushort_t*)d_ws;                  // 24*64*64*8 bf16 = 1.5 MB
    ushort_t* Bpl  = Bph + NTILE * 64 * 64 * 8;        // 1.5 MB
    float*    bias = (float*)(Bpl + NTILE * 64 * 64 * 8);
    float*    Yb   = bias + NPAD;                      // 16384*384 fp32

    jcp_repack3<<<384, 256, 0, stream>>>(W_fc, b_fc, W_bin, b_bin, W_res, b_res,
                                         Bph, Bpl, bias);
    jcp_gemm10<<<1024, 256, 0, stream>>>(x, Bph, Bpl, bias, Yb);
    jcp_head4<<<BROWS / 16, 256, 0, stream>>>(Yb, out);
}

// Round 7
// 274.493 us; speedup vs baseline: 1.0525x; 1.0525x over previous
//
#include <hip/hip_runtime.h>
#include <math.h>

// Problem constants
#define BROWS 16384
#define N0    2048
#define NCLS  12
#define NCLU  24
#define NDIM  4
#define NCOL  348          // 12 + 288 + 48
#define NPAD  384          // padded fused-column count (24 col-tiles of 16)
#define NTILE 24           // NPAD/16

// Output offsets (floats): y0 [B,12] | y1_sel [B,24] | y2_sel [B,4] | Plc [B,24,12]
#define OUT0_OFF 0
#define OUT1_OFF (BROWS * NCLS)
#define OUT2_OFF (OUT1_OFF + BROWS * NCLU)
#define OUT3_OFF (OUT2_OFF + BROWS * NDIM)

typedef __attribute__((ext_vector_type(8))) short bf16x8;
typedef __attribute__((ext_vector_type(4))) float f32x4;
typedef unsigned short ushort_t;

// ---------------------------------------------------------------------------
// bf16 helpers — RNE split (bit-identical to the passing numerics)
// ---------------------------------------------------------------------------
__device__ __forceinline__ unsigned short f2bf(float f) {   // RNE
    unsigned u = __float_as_uint(f);
    u += 0x7fffu + ((u >> 16) & 1u);
    return (unsigned short)(u >> 16);
}
__device__ __forceinline__ float bf2f(unsigned short h) {
    return __uint_as_float(((unsigned)h) << 16);
}

// Packed-HW cvt: v_cvt_pk_bf16_f32 is RNE — bit-identical to the integer
// split, ~3x fewer VALU ops. No builtin on gfx950 -> inline asm.
__device__ __forceinline__ void cvt8pk(float4 a, float4 b, bf16x8& h, bf16x8& l) {
    unsigned h0, h1, h2, h3;
    asm("v_cvt_pk_bf16_f32 %0, %1, %2" : "=v"(h0) : "v"(a.x), "v"(a.y));
    asm("v_cvt_pk_bf16_f32 %0, %1, %2" : "=v"(h1) : "v"(a.z), "v"(a.w));
    asm("v_cvt_pk_bf16_f32 %0, %1, %2" : "=v"(h2) : "v"(b.x), "v"(b.y));
    asm("v_cvt_pk_bf16_f32 %0, %1, %2" : "=v"(h3) : "v"(b.z), "v"(b.w));
    // lo-plane residuals: exact fp32 subtraction of the hi bf16 value
    float r0 = a.x - __uint_as_float(h0 << 16);
    float r1 = a.y - __uint_as_float(h0 & 0xffff0000u);
    float r2 = a.z - __uint_as_float(h1 << 16);
    float r3 = a.w - __uint_as_float(h1 & 0xffff0000u);
    float r4 = b.x - __uint_as_float(h2 << 16);
    float r5 = b.y - __uint_as_float(h2 & 0xffff0000u);
    float r6 = b.z - __uint_as_float(h3 << 16);
    float r7 = b.w - __uint_as_float(h3 & 0xffff0000u);
    unsigned l0, l1, l2, l3;
    asm("v_cvt_pk_bf16_f32 %0, %1, %2" : "=v"(l0) : "v"(r0), "v"(r1));
    asm("v_cvt_pk_bf16_f32 %0, %1, %2" : "=v"(l1) : "v"(r2), "v"(r3));
    asm("v_cvt_pk_bf16_f32 %0, %1, %2" : "=v"(l2) : "v"(r4), "v"(r5));
    asm("v_cvt_pk_bf16_f32 %0, %1, %2" : "=v"(l3) : "v"(r6), "v"(r7));
    union Pack { unsigned u[4]; bf16x8 v; };
    Pack H; H.u[0] = h0; H.u[1] = h1; H.u[2] = h2; H.u[3] = h3;
    Pack L; L.u[0] = l0; L.u[1] = l1; L.u[2] = l2; L.u[3] = l3;
    h = H.v;
    l = L.v;
}

__device__ __forceinline__ void load_lds16(const void* g, void* l) {
    __builtin_amdgcn_global_load_lds((const __attribute__((address_space(1))) void*)g,
                                     (__attribute__((address_space(3))) void*)l, 16, 0, 0);
}

__device__ __forceinline__ float fused_w(const float* __restrict__ W_fc,
                                         const float* __restrict__ W_bin,
                                         const float* __restrict__ W_res,
                                         int col, int d) {
    float w = 0.0f;
    if (col < NCLS) {
        w = W_fc[d * NCLS + col];
    } else if (col < 12 + NCLU * NCLS) {
        int jj = col - 12;
        int k = jj / NCLS, c = jj - k * NCLS;
        w = W_bin[((size_t)c * N0 + d) * NCLU + k];
    } else if (col < NCOL) {
        int jj = col - 300;
        int n = jj / NCLS, c = jj - n * NCLS;
        w = W_res[((size_t)c * N0 + d) * NDIM + n];
    }
    return w;
}

// ---------------------------------------------------------------------------
// Kernel 1: repack fused weights straight into MFMA-fragment streaming order.
//   Bp{h,l}[((J*64 + kb)*64 + lane)*8 + i] = W[col = J*16 + (lane&15)]
//                                             [k  = kb*32 + (lane>>4)*8 + i]
// ---------------------------------------------------------------------------
__global__ void jcp_repack3(const float* __restrict__ W_fc, const float* __restrict__ b_fc,
                            const float* __restrict__ W_bin, const float* __restrict__ b_bin,
                            const float* __restrict__ W_res, const float* __restrict__ b_res,
                            ushort_t* __restrict__ Bph, ushort_t* __restrict__ Bpl,
                            float* __restrict__ bias) {
    int t = blockIdx.x * 256 + threadIdx.x;          // 0 .. 98303
    if (t >= NTILE * 64 * 64) return;
    const int lane = t & 63;
    const int kb   = (t >> 6) & 63;
    const int J    = t >> 12;
    const int col  = J * 16 + (lane & 15);
    const int k0   = kb * 32 + (lane >> 4) * 8;

    bf16x8 h, l;
    #pragma unroll
    for (int i = 0; i < 8; ++i) {
        float w = fused_w(W_fc, W_bin, W_res, col, k0 + i);
        unsigned short hi = f2bf(w);
        h[i] = (short)hi;
        l[i] = (short)f2bf(w - bf2f(hi));
    }
    *(bf16x8*)(Bph + (size_t)t * 8) = h;
    *(bf16x8*)(Bpl + (size_t)t * 8) = l;

    if (t < NPAD) {
        int jb = t;
        float bv = 0.0f;
        if (jb < NCLS) {
            bv = b_fc[jb];
        } else if (jb < 12 + NCLU * NCLS) {
            int jj = jb - 12;
            int k = jj / NCLS, c = jj - k * NCLS;
            bv = b_bin[c * NCLU + k];
        } else if (jb < NCOL) {
            int jj = jb - 300;
            int n = jj / NCLS, c = jj - n * NCLS;
            bv = b_res[c * NDIM + n];
        }
        bias[jb] = bv;
    }
}

// ---------------------------------------------------------------------------
// Kernel 2: split-bf16 MFMA GEMM v11 — gemm9 geometry + register-level
//   fragment pipelining (frags for iter it converted one iteration ahead).
//   Grid 512 (XCD-bijective), block 256 = 4 waves, tile 128x96, 2 blocks/CU.
//   Body(it): refill(it+2) | 36 MFMA(it) [zero mem deps] | vmcnt(7)+barrier |
//             ds_read frags(it+1) | lgkm0 | cvt8pk(it+1) | barrier.
//   MFMAs no longer wait on their own ds_read+cvt chain; refill DMAs get a
//   full MFMA phase of head start. Same loads / cvt / MFMA order as gemm9
//   -> bit-identical output.
// ---------------------------------------------------------------------------
__global__ __launch_bounds__(256, 2) void jcp_gemm11(const float* __restrict__ x,
                                                     const ushort_t* __restrict__ Bph,
                                                     const ushort_t* __restrict__ Bpl,
                                                     const float* __restrict__ bias,
                                                     float* __restrict__ Y) {
    __shared__ float    Lx[2 * 4096];    // 2 bufs x 128 rows x 32 fp32 = 16 KB each
    __shared__ ushort_t Lb[2 * 6144];    // 2 bufs x 12 chunks x 512 ushorts = 12 KB each

    const int tid  = threadIdx.x;
    const int wid  = tid >> 6;
    const int lane = tid & 63;
    const int quad = lane >> 4;
    const int l16  = lane & 15;
    const int rg   = wid & 1;            // row half of block (64 rows)
    const int cg   = wid >> 1;           // col half of block (48 cols)

    // XCD-bijective decode: 4 col-blocks of a row-panel land on one XCD.
    const int g   = blockIdx.x;          // 0..511, 512 % 8 == 0 -> bijective
    const int xcd = g & 7;
    const int jj  = g >> 3;              // 0..63
    const int by  = xcd * 16 + (jj >> 2);
    const int bx  = jj & 3;
    const int rbase = by * 128;
    const int jbase = bx * 96;

    // --- x DMA (raw fp32): 4 insts/thread; inst n covers rows n*32 + (tid>>3),
    //     dest chunk tid&7 (16B units), source chunk XOR-swizzled by row. ---
    const int r0 = tid >> 3;             // 0..31
    const int c0 = tid & 7;
    const int o0 = c0 ^ (r0 & 7);        // (r0+32n)&7 == r0&7
    const float* gx = x + (size_t)(rbase + r0) * N0 + o0 * 4;   // + it*32 ; inst n: +n*65536
    // dest float offset: n*1024 + tid*4

    // --- B DMA: 3 insts/thread; wave w stages chunks w, 4+w, 8+w (1 KB each).
    const ushort_t* gb[3];
    int bdst[3];
    #pragma unroll
    for (int m = 0; m < 3; ++m) {
        const int c  = m * 4 + wid;                  // 0..11, wave-uniform
        const int J  = bx * 6 + (c >> 1);            // global col-tile 0..23
        const ushort_t* bp = (c & 1) ? Bpl : Bph;
        gb[m]   = bp + (size_t)J * 32768 + lane * 8; // + it*512 per iter
        bdst[m] = c * 512 + lane * 8;
    }

    // --- A fragment read offsets (floats), proven swizzled layout ---
    const int s  = l16 & 7;
    const int o1 = ((2 * quad) ^ s) * 4;
    const int o2 = o1 ^ 4;

    f32x4 acc[4][3];
    #pragma unroll
    for (int rt = 0; rt < 4; ++rt)
        #pragma unroll
        for (int j = 0; j < 3; ++j)
            acc[rt][j] = f32x4{0.f, 0.f, 0.f, 0.f};

    // Loop-carried fragment registers (frags for the iteration about to MFMA)
    bf16x8 Ah[4], Al[4], bh[3], bl[3];

    // Prologue: issue buf0's 7 DMAs (it=0), then buf1's 7 (it=1).
    #pragma unroll
    for (int n = 0; n < 4; ++n) load_lds16(gx + n * 65536, &Lx[n * 1024 + tid * 4]);
    #pragma unroll
    for (int m = 0; m < 3; ++m) load_lds16(gb[m], &Lb[bdst[m]]);
    #pragma unroll
    for (int n = 0; n < 4; ++n) load_lds16(gx + n * 65536 + 32, &Lx[4096 + n * 1024 + tid * 4]);
    #pragma unroll
    for (int m = 0; m < 3; ++m) load_lds16(gb[m] + 512, &Lb[6144 + bdst[m]]);
    asm volatile("s_waitcnt vmcnt(7)" ::: "memory");   // drain buf0's 7
    asm volatile("s_barrier" ::: "memory");
    {   // frags(0) from buf0 -> regs
        const float*    lx = &Lx[0];
        const ushort_t* lb = &Lb[0];
        float4 fa[4], fb[4];
        #pragma unroll
        for (int rt = 0; rt < 4; ++rt) {
            const int ro = (rg * 64 + rt * 16 + l16) * 32;
            fa[rt] = *(const float4*)&lx[ro + o1];
            fb[rt] = *(const float4*)&lx[ro + o2];
        }
        #pragma unroll
        for (int j = 0; j < 3; ++j) {
            const int ch = (cg * 3 + j) * 2;
            bh[j] = *(const bf16x8*)(lb + ch * 512 + lane * 8);
            bl[j] = *(const bf16x8*)(lb + ch * 512 + 512 + lane * 8);
        }
        asm volatile("s_waitcnt lgkmcnt(0)" ::: "memory");
        #pragma unroll
        for (int rt = 0; rt < 4; ++rt) cvt8pk(fa[rt], fb[rt], Ah[rt], Al[rt]);
        asm volatile("s_barrier" ::: "memory");   // all waves done reading buf0
    }

    int p = 0;                       // p == it % 2 at body entry
    for (int it = 0; it < 62; ++it) {
        // Refill buf p with data(it+2) (reads of buf p finished last body).
        #pragma unroll
        for (int n = 0; n < 4; ++n)
            load_lds16(gx + n * 65536 + (it + 2) * 32,
                       &Lx[p * 4096 + n * 1024 + tid * 4]);
        #pragma unroll
        for (int m = 0; m < 3; ++m)
            load_lds16(gb[m] + (it + 2) * 512, &Lb[p * 6144 + bdst[m]]);
        __builtin_amdgcn_sched_barrier(0);   // keep DMA issue ahead of MFMAs

        // 36 MFMAs on frags(it) — zero dependence on this body's memory ops.
        __builtin_amdgcn_s_setprio(1);
        #pragma unroll
        for (int j = 0; j < 3; ++j)
            #pragma unroll
            for (int rt = 0; rt < 4; ++rt) {
                acc[rt][j] = __builtin_amdgcn_mfma_f32_16x16x32_bf16(Ah[rt], bh[j], acc[rt][j], 0, 0, 0);
                acc[rt][j] = __builtin_amdgcn_mfma_f32_16x16x32_bf16(Al[rt], bh[j], acc[rt][j], 0, 0, 0);
                acc[rt][j] = __builtin_amdgcn_mfma_f32_16x16x32_bf16(Ah[rt], bl[j], acc[rt][j], 0, 0, 0);
            }
        __builtin_amdgcn_s_setprio(0);

        // data(it+1) ready in buf p^1 (its 7 DMAs are the oldest in flight).
        asm volatile("s_waitcnt vmcnt(7)" ::: "memory");
        asm volatile("s_barrier" ::: "memory");

        // ds_read + cvt frags(it+1) -> regs for next body.
        const float*    lx = &Lx[(p ^ 1) * 4096];
        const ushort_t* lb = &Lb[(p ^ 1) * 6144];
        float4 fa[4], fb[4];
        #pragma unroll
        for (int rt = 0; rt < 4; ++rt) {
            const int ro = (rg * 64 + rt * 16 + l16) * 32;
            fa[rt] = *(const float4*)&lx[ro + o1];
            fb[rt] = *(const float4*)&lx[ro + o2];
        }
        #pragma unroll
        for (int j = 0; j < 3; ++j) {
            const int ch = (cg * 3 + j) * 2;
            bh[j] = *(const bf16x8*)(lb + ch * 512 + lane * 8);
            bl[j] = *(const bf16x8*)(lb + ch * 512 + 512 + lane * 8);
        }
        asm volatile("s_waitcnt lgkmcnt(0)" ::: "memory");
        #pragma unroll
        for (int rt = 0; rt < 4; ++rt) cvt8pk(fa[rt], fb[rt], Ah[rt], Al[rt]);
        asm volatile("s_barrier" ::: "memory");   // reads of buf p^1 done
        p ^= 1;
    }

    // it = 62 peeled: MFMA(62), then drain refill(63) fully and read frags(63).
    {
        __builtin_amdgcn_s_setprio(1);
        #pragma unroll
        for (int j = 0; j < 3; ++j)
            #pragma unroll
            for (int rt = 0; rt < 4; ++rt) {
                acc[rt][j] = __builtin_amdgcn_mfma_f32_16x16x32_bf16(Ah[rt], bh[j], acc[rt][j], 0, 0, 0);
                acc[rt][j] = __builtin_amdgcn_mfma_f32_16x16x32_bf16(Al[rt], bh[j], acc[rt][j], 0, 0, 0);
                acc[rt][j] = __builtin_amdgcn_mfma_f32_16x16x32_bf16(Ah[rt], bl[j], acc[rt][j], 0, 0, 0);
            }
        __builtin_amdgcn_s_setprio(0);
        asm volatile("s_waitcnt vmcnt(0)" ::: "memory");
        asm volatile("s_barrier" ::: "memory");
        const float*    lx = &Lx[(p ^ 1) * 4096];   // p==0 -> buf1 holds data(63)
        const ushort_t* lb = &Lb[(p ^ 1) * 6144];
        float4 fa[4], fb[4];
        #pragma unroll
        for (int rt = 0; rt < 4; ++rt) {
            const int ro = (rg * 64 + rt * 16 + l16) * 32;
            fa[rt] = *(const float4*)&lx[ro + o1];
            fb[rt] = *(const float4*)&lx[ro + o2];
        }
        #pragma unroll
        for (int j = 0; j < 3; ++j) {
            const int ch = (cg * 3 + j) * 2;
            bh[j] = *(const bf16x8*)(lb + ch * 512 + lane * 8);
            bl[j] = *(const bf16x8*)(lb + ch * 512 + 512 + lane * 8);
        }
        asm volatile("s_waitcnt lgkmcnt(0)" ::: "memory");
        #pragma unroll
        for (int rt = 0; rt < 4; ++rt) cvt8pk(fa[rt], fb[rt], Ah[rt], Al[rt]);
        // final MFMA(63)
        #pragma unroll
        for (int j = 0; j < 3; ++j)
            #pragma unroll
            for (int rt = 0; rt < 4; ++rt) {
                acc[rt][j] = __builtin_amdgcn_mfma_f32_16x16x32_bf16(Ah[rt], bh[j], acc[rt][j], 0, 0, 0);
                acc[rt][j] = __builtin_amdgcn_mfma_f32_16x16x32_bf16(Al[rt], bh[j], acc[rt][j], 0, 0, 0);
                acc[rt][j] = __builtin_amdgcn_mfma_f32_16x16x32_bf16(Ah[rt], bl[j], acc[rt][j], 0, 0, 0);
            }
    }

    // Epilogue: C/D layout col = lane&15, row = quad*4 + reg
    #pragma unroll
    for (int j = 0; j < 3; ++j) {
        const int col = jbase + cg * 48 + 16 * j + l16;
        const float bj = bias[col];
        #pragma unroll
        for (int rt = 0; rt < 4; ++rt) {
            float* yp = Y + (size_t)(rbase + rg * 64 + rt * 16 + quad * 4) * NPAD + col;
            yp[0 * NPAD] = acc[rt][j][0] + bj;
            yp[1 * NPAD] = acc[rt][j][1] + bj;
            yp[2 * NPAD] = acc[rt][j][2] + bj;
            yp[3 * NPAD] = acc[rt][j][3] + bj;
        }
    }
}

// ---------------------------------------------------------------------------
// Kernel 3: head v4. Block = 256 thr = 16 rows x 16 lanes (lane = class).
// ---------------------------------------------------------------------------
#define LROW 388   // padded LDS row stride (floats)

__global__ __launch_bounds__(256) void jcp_head4(const float* __restrict__ Y,
                                                 float* __restrict__ out) {
    __shared__ float Ly[16 * LROW];
    const int tid = threadIdx.x;
    const int r0  = blockIdx.x * 16;

    #pragma unroll
    for (int jj = 0; jj < 6; ++jj) {
        int f = tid + jj * 256;
        int row = f / 96, c4 = f - row * 96;
        float4 v = *(const float4*)(Y + (size_t)(r0 + row) * NPAD + c4 * 4);
        *(float4*)&Ly[row * LROW + c4 * 4] = v;
    }
    __syncthreads();

    const int grp = tid >> 4;
    const int c   = tid & 15;
    const bool on = (c < NCLS);
    const int r   = r0 + grp;
    const float* y = &Ly[grp * LROW];

    float y0c = on ? y[c] : -INFINITY;
    float m0 = y0c;
    #pragma unroll
    for (int m = 8; m >= 1; m >>= 1) m0 = fmaxf(m0, __shfl_xor(m0, m, 16));
    float e0 = on ? expf(y0c - m0) : 0.0f;
    float s0 = e0;
    #pragma unroll
    for (int m = 8; m >= 1; m >>= 1) s0 += __shfl_xor(s0, m, 16);
    const float Pc = e0 / s0;

    float v[NCLU];
    float mc = -INFINITY;
    #pragma unroll
    for (int k = 0; k < NCLU; ++k) {
        v[k] = y[12 + k * NCLS + c];
        mc = fmaxf(mc, v[k]);
    }
    float ev[NCLU];
    float sc = 0.0f;
    #pragma unroll
    for (int k = 0; k < NCLU; ++k) { ev[k] = expf(v[k] - mc); sc += ev[k]; }
    const float rs = Pc / sc;

    float y2c[NDIM];
    #pragma unroll
    for (int n = 0; n < NDIM; ++n) y2c[n] = y[300 + n * NCLS + c];

    float best = -INFINITY;
    int bk = 0;
    float* lrow = &Ly[grp * LROW];
    #pragma unroll
    for (int k = 0; k < NCLU; ++k) {
        const float p = ev[k] * rs;
        if (on) lrow[k * NCLS + c] = p;
        if (p > best) { best = p; bk = k; }
    }
    int flat = bk * NCLS + c;
    if (!on) { best = -INFINITY; flat = 1 << 30; }

    #pragma unroll
    for (int m = 8; m >= 1; m >>= 1) {
        const float op = __shfl_xor(best, m, 16);
        const int   of = __shfl_xor(flat, m, 16);
        if (op > best || (op == best && of < flat)) { best = op; flat = of; }
    }
    const int ic = flat % NCLS;

    if (on) out[OUT0_OFF + (size_t)r * NCLS + c] = y0c;
    if (c == ic) {
        float* o1 = out + OUT1_OFF + (size_t)r * NCLU;
        #pragma unroll
        for (int k = 0; k < NCLU; ++k) o1[k] = v[k];
        float* o2 = out + OUT2_OFF + (size_t)r * NDIM;
        #pragma unroll
        for (int n = 0; n < NDIM; ++n) o2[n] = y2c[n];
    }

    __syncthreads();
    #pragma unroll
    for (int jj = 0; jj < 5; ++jj) {
        int f = tid + jj * 256;
        if (f < 1152) {
            int row = f / 72, c4 = f - row * 72;
            *(float4*)(out + OUT3_OFF + (size_t)(r0 + row) * (NCLU * NCLS) + c4 * 4) =
                *(float4*)&Ly[row * LROW + c4 * 4];
        }
    }
}

// ---------------------------------------------------------------------------
extern "C" void kernel_launch(void* const* d_in, const int* in_sizes, int n_in,
                              void* d_out, int out_size, void* d_ws, size_t ws_size,
                              hipStream_t stream) {
    const float* x     = (const float*)d_in[0];
    const float* W_fc  = (const float*)d_in[1];
    const float* b_fc  = (const float*)d_in[2];
    const float* W_bin = (const float*)d_in[3];
    const float* b_bin = (const float*)d_in[4];
    const float* W_res = (const float*)d_in[5];
    const float* b_res = (const float*)d_in[6];
    float* out = (float*)d_out;

    // ws layout (bytes): Bph 1.5MB | Bpl 1.5MB | bias 1.5KB | Y 25.2MB
    ushort_t* Bph  = (ushort_t*)d_ws;                  // 24*64*64*8 bf16 = 1.5 MB
    ushort_t* Bpl  = Bph + NTILE * 64 * 64 * 8;        // 1.5 MB
    float*    bias = (float*)(Bpl + NTILE * 64 * 64 * 8);
    float*    Yb   = bias + NPAD;                      // 16384*384 fp32

    jcp_repack3<<<384, 256, 0, stream>>>(W_fc, b_fc, W_bin, b_bin, W_res, b_res,
                                         Bph, Bpl, bias);
    jcp_gemm11<<<512, 256, 0, stream>>>(x, Bph, Bpl, bias, Yb);
    jcp_head4<<<BROWS / 16, 256, 0, stream>>>(Yb, out);
}

// Round 8
// 273.963 us; speedup vs baseline: 1.0546x; 1.0019x over previous
//
#include <hip/hip_runtime.h>
#include <math.h>

// Problem constants
#define BROWS 16384
#define N0    2048
#define NCLS  12
#define NCLU  24
#define NDIM  4
#define NCOL  348          // 12 + 288 + 48
#define NPAD  384          // padded fused-column count (24 col-tiles of 16)
#define NTILE 24           // NPAD/16

// Output offsets (floats): y0 [B,12] | y1_sel [B,24] | y2_sel [B,4] | Plc [B,24,12]
#define OUT0_OFF 0
#define OUT1_OFF (BROWS * NCLS)
#define OUT2_OFF (OUT1_OFF + BROWS * NCLU)
#define OUT3_OFF (OUT2_OFF + BROWS * NDIM)

typedef __attribute__((ext_vector_type(8))) short bf16x8;
typedef __attribute__((ext_vector_type(4))) float f32x4;
typedef unsigned short ushort_t;

// ---------------------------------------------------------------------------
// bf16 helpers — RNE split (bit-identical to the passing numerics)
// ---------------------------------------------------------------------------
__device__ __forceinline__ unsigned short f2bf(float f) {   // RNE
    unsigned u = __float_as_uint(f);
    u += 0x7fffu + ((u >> 16) & 1u);
    return (unsigned short)(u >> 16);
}
__device__ __forceinline__ float bf2f(unsigned short h) {
    return __uint_as_float(((unsigned)h) << 16);
}

// Packed-HW cvt: v_cvt_pk_bf16_f32 is RNE — bit-identical to the integer
// split, ~3x fewer VALU ops. No builtin on gfx950 -> inline asm.
__device__ __forceinline__ void cvt8pk(float4 a, float4 b, bf16x8& h, bf16x8& l) {
    unsigned h0, h1, h2, h3;
    asm("v_cvt_pk_bf16_f32 %0, %1, %2" : "=v"(h0) : "v"(a.x), "v"(a.y));
    asm("v_cvt_pk_bf16_f32 %0, %1, %2" : "=v"(h1) : "v"(a.z), "v"(a.w));
    asm("v_cvt_pk_bf16_f32 %0, %1, %2" : "=v"(h2) : "v"(b.x), "v"(b.y));
    asm("v_cvt_pk_bf16_f32 %0, %1, %2" : "=v"(h3) : "v"(b.z), "v"(b.w));
    // lo-plane residuals: exact fp32 subtraction of the hi bf16 value
    float r0 = a.x - __uint_as_float(h0 << 16);
    float r1 = a.y - __uint_as_float(h0 & 0xffff0000u);
    float r2 = a.z - __uint_as_float(h1 << 16);
    float r3 = a.w - __uint_as_float(h1 & 0xffff0000u);
    float r4 = b.x - __uint_as_float(h2 << 16);
    float r5 = b.y - __uint_as_float(h2 & 0xffff0000u);
    float r6 = b.z - __uint_as_float(h3 << 16);
    float r7 = b.w - __uint_as_float(h3 & 0xffff0000u);
    unsigned l0, l1, l2, l3;
    asm("v_cvt_pk_bf16_f32 %0, %1, %2" : "=v"(l0) : "v"(r0), "v"(r1));
    asm("v_cvt_pk_bf16_f32 %0, %1, %2" : "=v"(l1) : "v"(r2), "v"(r3));
    asm("v_cvt_pk_bf16_f32 %0, %1, %2" : "=v"(l2) : "v"(r4), "v"(r5));
    asm("v_cvt_pk_bf16_f32 %0, %1, %2" : "=v"(l3) : "v"(r6), "v"(r7));
    union Pack { unsigned u[4]; bf16x8 v; };
    Pack H; H.u[0] = h0; H.u[1] = h1; H.u[2] = h2; H.u[3] = h3;
    Pack L; L.u[0] = l0; L.u[1] = l1; L.u[2] = l2; L.u[3] = l3;
    h = H.v;
    l = L.v;
}

__device__ __forceinline__ void load_lds16(const void* g, void* l) {
    __builtin_amdgcn_global_load_lds((const __attribute__((address_space(1))) void*)g,
                                     (__attribute__((address_space(3))) void*)l, 16, 0, 0);
}

__device__ __forceinline__ float fused_w(const float* __restrict__ W_fc,
                                         const float* __restrict__ W_bin,
                                         const float* __restrict__ W_res,
                                         int col, int d) {
    float w = 0.0f;
    if (col < NCLS) {
        w = W_fc[d * NCLS + col];
    } else if (col < 12 + NCLU * NCLS) {
        int jj = col - 12;
        int k = jj / NCLS, c = jj - k * NCLS;
        w = W_bin[((size_t)c * N0 + d) * NCLU + k];
    } else if (col < NCOL) {
        int jj = col - 300;
        int n = jj / NCLS, c = jj - n * NCLS;
        w = W_res[((size_t)c * N0 + d) * NDIM + n];
    }
    return w;
}

// ---------------------------------------------------------------------------
// Kernel 1: repack fused weights straight into MFMA-fragment streaming order.
//   Bp{h,l}[((J*64 + kb)*64 + lane)*8 + i] = W[col = J*16 + (lane&15)]
//                                             [k  = kb*32 + (lane>>4)*8 + i]
// ---------------------------------------------------------------------------
__global__ void jcp_repack3(const float* __restrict__ W_fc, const float* __restrict__ b_fc,
                            const float* __restrict__ W_bin, const float* __restrict__ b_bin,
                            const float* __restrict__ W_res, const float* __restrict__ b_res,
                            ushort_t* __restrict__ Bph, ushort_t* __restrict__ Bpl,
                            float* __restrict__ bias) {
    int t = blockIdx.x * 256 + threadIdx.x;          // 0 .. 98303
    if (t >= NTILE * 64 * 64) return;
    const int lane = t & 63;
    const int kb   = (t >> 6) & 63;
    const int J    = t >> 12;
    const int col  = J * 16 + (lane & 15);
    const int k0   = kb * 32 + (lane >> 4) * 8;

    bf16x8 h, l;
    #pragma unroll
    for (int i = 0; i < 8; ++i) {
        float w = fused_w(W_fc, W_bin, W_res, col, k0 + i);
        unsigned short hi = f2bf(w);
        h[i] = (short)hi;
        l[i] = (short)f2bf(w - bf2f(hi));
    }
    *(bf16x8*)(Bph + (size_t)t * 8) = h;
    *(bf16x8*)(Bpl + (size_t)t * 8) = l;

    if (t < NPAD) {
        int jb = t;
        float bv = 0.0f;
        if (jb < NCLS) {
            bv = b_fc[jb];
        } else if (jb < 12 + NCLU * NCLS) {
            int jj = jb - 12;
            int k = jj / NCLS, c = jj - k * NCLS;
            bv = b_bin[c * NCLU + k];
        } else if (jb < NCOL) {
            int jj = jb - 300;
            int n = jj / NCLS, c = jj - n * NCLS;
            bv = b_res[c * NDIM + n];
        }
        bias[jb] = bv;
    }
}

// ---------------------------------------------------------------------------
// Kernel 2: split-bf16 MFMA GEMM v12 — B direct global->register (no LDS).
//   Grid 512 (XCD-bijective), block 256 = 4 waves, tile 128x96, 2 blocks/CU.
//   LDS = x only (2 x 16 KB). LDS reads/thread/iter 14 -> 8 (A frags only);
//   DMAs/buffer 7 -> 4. B fragments (L2-resident, fragment-ordered Bp) are
//   loaded one iteration ahead into a double-buffered register set — a pure
//   per-wave pipeline with no barrier dependency.
//   Per body (order pinned by sched_barrier fences; loop unrolled 2x so all
//   buffer/register indices are literals):
//     [B(it+1) 6 loads][x(it+2) 4 DMAs] | MFMA(it) | vmcnt(10)+barrier
//     (drains x(it+1), always the 4 oldest) | ds_read A(it+1)+cvt |
//     vmcnt(4) (B regs landed) | barrier.
//   Same loads / cvt8pk / MFMA order as gemm9/11 -> bit-identical output.
// ---------------------------------------------------------------------------
#define GBODY(CUR, NXT, PBUF, RBUF, IT)                                        \
    {                                                                          \
        _Pragma("unroll")                                                      \
        for (int j = 0; j < 3; ++j) {                                          \
            bh[NXT][j] = *(const bf16x8*)(pBh + Jt3[j] + ((IT) + 1) * 512);    \
            bl[NXT][j] = *(const bf16x8*)(pBl + Jt3[j] + ((IT) + 1) * 512);    \
        }                                                                      \
        __builtin_amdgcn_sched_barrier(0);                                     \
        _Pragma("unroll")                                                      \
        for (int n = 0; n < 4; ++n)                                            \
            load_lds16(gx + n * 65536 + ((IT) + 2) * 32,                       \
                       &Lx[(PBUF) * 4096 + n * 1024 + tid * 4]);               \
        __builtin_amdgcn_sched_barrier(0);                                     \
        __builtin_amdgcn_s_setprio(1);                                         \
        _Pragma("unroll")                                                      \
        for (int j = 0; j < 3; ++j) {                                          \
            _Pragma("unroll")                                                  \
            for (int rt = 0; rt < 4; ++rt) {                                   \
                acc[rt][j] = __builtin_amdgcn_mfma_f32_16x16x32_bf16(          \
                    Ah[CUR][rt], bh[CUR][j], acc[rt][j], 0, 0, 0);             \
                acc[rt][j] = __builtin_amdgcn_mfma_f32_16x16x32_bf16(          \
                    Al[CUR][rt], bh[CUR][j], acc[rt][j], 0, 0, 0);             \
                acc[rt][j] = __builtin_amdgcn_mfma_f32_16x16x32_bf16(          \
                    Ah[CUR][rt], bl[CUR][j], acc[rt][j], 0, 0, 0);             \
            }                                                                  \
        }                                                                      \
        __builtin_amdgcn_s_setprio(0);                                         \
        asm volatile("s_waitcnt vmcnt(10)" ::: "memory");                      \
        asm volatile("s_barrier" ::: "memory");                                \
        __builtin_amdgcn_sched_barrier(0);                                     \
        {                                                                      \
            const float* lx = &Lx[(RBUF) * 4096];                              \
            _Pragma("unroll")                                                  \
            for (int rt = 0; rt < 4; ++rt) {                                   \
                const int ro = (rg * 64 + rt * 16 + l16) * 32;                 \
                fa4[rt] = *(const float4*)&lx[ro + o1];                        \
                fb4[rt] = *(const float4*)&lx[ro + o2];                        \
            }                                                                  \
            asm volatile("s_waitcnt lgkmcnt(0)" ::: "memory");                 \
            __builtin_amdgcn_sched_barrier(0);                                 \
            _Pragma("unroll")                                                  \
            for (int rt = 0; rt < 4; ++rt)                                     \
                cvt8pk(fa4[rt], fb4[rt], Ah[NXT][rt], Al[NXT][rt]);            \
        }                                                                      \
        asm volatile("s_waitcnt vmcnt(4)" ::: "memory");                       \
        __builtin_amdgcn_sched_barrier(0);                                     \
        asm volatile("s_barrier" ::: "memory");                                \
    }

__global__ __launch_bounds__(256, 2) void jcp_gemm12(const float* __restrict__ x,
                                                     const ushort_t* __restrict__ Bph,
                                                     const ushort_t* __restrict__ Bpl,
                                                     const float* __restrict__ bias,
                                                     float* __restrict__ Y) {
    __shared__ float Lx[2 * 4096];    // 2 bufs x 128 rows x 32 fp32 = 16 KB each

    const int tid  = threadIdx.x;
    const int wid  = tid >> 6;
    const int lane = tid & 63;
    const int quad = lane >> 4;
    const int l16  = lane & 15;
    const int rg   = wid & 1;            // row half of block (64 rows)
    const int cg   = wid >> 1;           // col half of block (48 cols)

    // XCD-bijective decode: 4 col-blocks of a row-panel land on one XCD.
    const int g   = blockIdx.x;          // 0..511, 512 % 8 == 0 -> bijective
    const int xcd = g & 7;
    const int jj  = g >> 3;              // 0..63
    const int by  = xcd * 16 + (jj >> 2);
    const int bx  = jj & 3;
    const int rbase = by * 128;
    const int jbase = bx * 96;

    // --- x DMA (raw fp32): 4 insts/thread; inst n covers rows n*32 + (tid>>3),
    //     dest chunk tid&7 (16B units), source chunk XOR-swizzled by row. ---
    const int r0 = tid >> 3;             // 0..31
    const int c0 = tid & 7;
    const int o0 = c0 ^ (r0 & 7);        // (r0+32n)&7 == r0&7
    const float* gx = x + (size_t)(rbase + r0) * N0 + o0 * 4;   // + it*32 ; inst n: +n*65536

    // --- B direct-load pointers: wave reads col-tiles bx*6 + cg*3 + j, both
    //     planes, fragment-ordered & coalesced (16B/lane). ---
    const ushort_t* pBh = Bph + (size_t)lane * 8;
    const ushort_t* pBl = Bpl + (size_t)lane * 8;
    int Jt3[3];
    #pragma unroll
    for (int j = 0; j < 3; ++j) Jt3[j] = (bx * 6 + cg * 3 + j) * 32768;

    // --- A fragment read offsets (floats), proven swizzled layout ---
    const int s  = l16 & 7;
    const int o1 = ((2 * quad) ^ s) * 4;
    const int o2 = o1 ^ 4;

    f32x4 acc[4][3];
    #pragma unroll
    for (int rt = 0; rt < 4; ++rt)
        #pragma unroll
        for (int j = 0; j < 3; ++j)
            acc[rt][j] = f32x4{0.f, 0.f, 0.f, 0.f};

    // Double-buffered fragment register sets + transient read regs.
    bf16x8 Ah[2][4], Al[2][4], bh[2][3], bl[2][3];
    float4 fa4[4], fb4[4];

    // Prologue: x(0)->buf0 [4], B(0)->set0 [6], x(1)->buf1 [4]  (14 in flight)
    #pragma unroll
    for (int n = 0; n < 4; ++n) load_lds16(gx + n * 65536, &Lx[n * 1024 + tid * 4]);
    __builtin_amdgcn_sched_barrier(0);
    #pragma unroll
    for (int j = 0; j < 3; ++j) {
        bh[0][j] = *(const bf16x8*)(pBh + Jt3[j]);
        bl[0][j] = *(const bf16x8*)(pBl + Jt3[j]);
    }
    __builtin_amdgcn_sched_barrier(0);
    #pragma unroll
    for (int n = 0; n < 4; ++n) load_lds16(gx + n * 65536 + 32, &Lx[4096 + n * 1024 + tid * 4]);
    __builtin_amdgcn_sched_barrier(0);
    asm volatile("s_waitcnt vmcnt(10)" ::: "memory");   // x(0) done (4 oldest)
    asm volatile("s_barrier" ::: "memory");
    __builtin_amdgcn_sched_barrier(0);
    {   // A(0) from buf0 -> set0
        const float* lx = &Lx[0];
        #pragma unroll
        for (int rt = 0; rt < 4; ++rt) {
            const int ro = (rg * 64 + rt * 16 + l16) * 32;
            fa4[rt] = *(const float4*)&lx[ro + o1];
            fb4[rt] = *(const float4*)&lx[ro + o2];
        }
        asm volatile("s_waitcnt lgkmcnt(0)" ::: "memory");
        __builtin_amdgcn_sched_barrier(0);
        #pragma unroll
        for (int rt = 0; rt < 4; ++rt) cvt8pk(fa4[rt], fb4[rt], Ah[0][rt], Al[0][rt]);
    }
    asm volatile("s_waitcnt vmcnt(4)" ::: "memory");    // B(0) regs landed
    __builtin_amdgcn_sched_barrier(0);
    asm volatile("s_barrier" ::: "memory");             // reads of buf0 done

    // Main loop: 62 bodies, 2x unrolled (literal indices everywhere).
    for (int it = 0; it < 62; it += 2) {
        GBODY(0, 1, 0, 1, it);
        GBODY(1, 0, 1, 0, it + 1);
    }

    // Peeled body(62): set0 holds frags(62); buf1 holds x(63); x(63) 4 in flight.
    {
        #pragma unroll
        for (int j = 0; j < 3; ++j) {
            bh[1][j] = *(const bf16x8*)(pBh + Jt3[j] + 63 * 512);
            bl[1][j] = *(const bf16x8*)(pBl + Jt3[j] + 63 * 512);
        }
        __builtin_amdgcn_sched_barrier(0);
        __builtin_amdgcn_s_setprio(1);
        #pragma unroll
        for (int j = 0; j < 3; ++j)
            #pragma unroll
            for (int rt = 0; rt < 4; ++rt) {
                acc[rt][j] = __builtin_amdgcn_mfma_f32_16x16x32_bf16(Ah[0][rt], bh[0][j], acc[rt][j], 0, 0, 0);
                acc[rt][j] = __builtin_amdgcn_mfma_f32_16x16x32_bf16(Al[0][rt], bh[0][j], acc[rt][j], 0, 0, 0);
                acc[rt][j] = __builtin_amdgcn_mfma_f32_16x16x32_bf16(Ah[0][rt], bl[0][j], acc[rt][j], 0, 0, 0);
            }
        __builtin_amdgcn_s_setprio(0);
        asm volatile("s_waitcnt vmcnt(6)" ::: "memory");   // x(63) done
        asm volatile("s_barrier" ::: "memory");
        __builtin_amdgcn_sched_barrier(0);
        const float* lx = &Lx[4096];
        #pragma unroll
        for (int rt = 0; rt < 4; ++rt) {
            const int ro = (rg * 64 + rt * 16 + l16) * 32;
            fa4[rt] = *(const float4*)&lx[ro + o1];
            fb4[rt] = *(const float4*)&lx[ro + o2];
        }
        asm volatile("s_waitcnt lgkmcnt(0)" ::: "memory");
        __builtin_amdgcn_sched_barrier(0);
        #pragma unroll
        for (int rt = 0; rt < 4; ++rt) cvt8pk(fa4[rt], fb4[rt], Ah[1][rt], Al[1][rt]);
        asm volatile("s_waitcnt vmcnt(0)" ::: "memory");   // B(63) regs landed
        __builtin_amdgcn_sched_barrier(0);
        #pragma unroll
        for (int j = 0; j < 3; ++j)
            #pragma unroll
            for (int rt = 0; rt < 4; ++rt) {
                acc[rt][j] = __builtin_amdgcn_mfma_f32_16x16x32_bf16(Ah[1][rt], bh[1][j], acc[rt][j], 0, 0, 0);
                acc[rt][j] = __builtin_amdgcn_mfma_f32_16x16x32_bf16(Al[1][rt], bh[1][j], acc[rt][j], 0, 0, 0);
                acc[rt][j] = __builtin_amdgcn_mfma_f32_16x16x32_bf16(Ah[1][rt], bl[1][j], acc[rt][j], 0, 0, 0);
            }
    }

    // Epilogue: C/D layout col = lane&15, row = quad*4 + reg
    #pragma unroll
    for (int j = 0; j < 3; ++j) {
        const int col = jbase + cg * 48 + 16 * j + l16;
        const float bj = bias[col];
        #pragma unroll
        for (int rt = 0; rt < 4; ++rt) {
            float* yp = Y + (size_t)(rbase + rg * 64 + rt * 16 + quad * 4) * NPAD + col;
            yp[0 * NPAD] = acc[rt][j][0] + bj;
            yp[1 * NPAD] = acc[rt][j][1] + bj;
            yp[2 * NPAD] = acc[rt][j][2] + bj;
            yp[3 * NPAD] = acc[rt][j][3] + bj;
        }
    }
}

// ---------------------------------------------------------------------------
// Kernel 3: head v4. Block = 256 thr = 16 rows x 16 lanes (lane = class).
// ---------------------------------------------------------------------------
#define LROW 388   // padded LDS row stride (floats)

__global__ __launch_bounds__(256) void jcp_head4(const float* __restrict__ Y,
                                                 float* __restrict__ out) {
    __shared__ float Ly[16 * LROW];
    const int tid = threadIdx.x;
    const int r0  = blockIdx.x * 16;

    #pragma unroll
    for (int jj = 0; jj < 6; ++jj) {
        int f = tid + jj * 256;
        int row = f / 96, c4 = f - row * 96;
        float4 v = *(const float4*)(Y + (size_t)(r0 + row) * NPAD + c4 * 4);
        *(float4*)&Ly[row * LROW + c4 * 4] = v;
    }
    __syncthreads();

    const int grp = tid >> 4;
    const int c   = tid & 15;
    const bool on = (c < NCLS);
    const int r   = r0 + grp;
    const float* y = &Ly[grp * LROW];

    float y0c = on ? y[c] : -INFINITY;
    float m0 = y0c;
    #pragma unroll
    for (int m = 8; m >= 1; m >>= 1) m0 = fmaxf(m0, __shfl_xor(m0, m, 16));
    float e0 = on ? expf(y0c - m0) : 0.0f;
    float s0 = e0;
    #pragma unroll
    for (int m = 8; m >= 1; m >>= 1) s0 += __shfl_xor(s0, m, 16);
    const float Pc = e0 / s0;

    float v[NCLU];
    float mc = -INFINITY;
    #pragma unroll
    for (int k = 0; k < NCLU; ++k) {
        v[k] = y[12 + k * NCLS + c];
        mc = fmaxf(mc, v[k]);
    }
    float ev[NCLU];
    float sc = 0.0f;
    #pragma unroll
    for (int k = 0; k < NCLU; ++k) { ev[k] = expf(v[k] - mc); sc += ev[k]; }
    const float rs = Pc / sc;

    float y2c[NDIM];
    #pragma unroll
    for (int n = 0; n < NDIM; ++n) y2c[n] = y[300 + n * NCLS + c];

    float best = -INFINITY;
    int bk = 0;
    float* lrow = &Ly[grp * LROW];
    #pragma unroll
    for (int k = 0; k < NCLU; ++k) {
        const float p = ev[k] * rs;
        if (on) lrow[k * NCLS + c] = p;
        if (p > best) { best = p; bk = k; }
    }
    int flat = bk * NCLS + c;
    if (!on) { best = -INFINITY; flat = 1 << 30; }

    #pragma unroll
    for (int m = 8; m >= 1; m >>= 1) {
        const float op = __shfl_xor(best, m, 16);
        const int   of = __shfl_xor(flat, m, 16);
        if (op > best || (op == best && of < flat)) { best = op; flat = of; }
    }
    const int ic = flat % NCLS;

    if (on) out[OUT0_OFF + (size_t)r * NCLS + c] = y0c;
    if (c == ic) {
        float* o1v = out + OUT1_OFF + (size_t)r * NCLU;
        #pragma unroll
        for (int k = 0; k < NCLU; ++k) o1v[k] = v[k];
        float* o2v = out + OUT2_OFF + (size_t)r * NDIM;
        #pragma unroll
        for (int n = 0; n < NDIM; ++n) o2v[n] = y2c[n];
    }

    __syncthreads();
    #pragma unroll
    for (int jj = 0; jj < 5; ++jj) {
        int f = tid + jj * 256;
        if (f < 1152) {
            int row = f / 72, c4 = f - row * 72;
            *(float4*)(out + OUT3_OFF + (size_t)(r0 + row) * (NCLU * NCLS) + c4 * 4) =
                *(float4*)&Ly[row * LROW + c4 * 4];
        }
    }
}

// ---------------------------------------------------------------------------
extern "C" void kernel_launch(void* const* d_in, const int* in_sizes, int n_in,
                              void* d_out, int out_size, void* d_ws, size_t ws_size,
                              hipStream_t stream) {
    const float* x     = (const float*)d_in[0];
    const float* W_fc  = (const float*)d_in[1];
    const float* b_fc  = (const float*)d_in[2];
    const float* W_bin = (const float*)d_in[3];
    const float* b_bin = (const float*)d_in[4];
    const float* W_res = (const float*)d_in[5];
    const float* b_res = (const float*)d_in[6];
    float* out = (float*)d_out;

    // ws layout (bytes): Bph 1.5MB | Bpl 1.5MB | bias 1.5KB | Y 25.2MB
    ushort_t* Bph  = (ushort_t*)d_ws;                  // 24*64*64*8 bf16 = 1.5 MB
    ushort_t* Bpl  = Bph + NTILE * 64 * 64 * 8;        // 1.5 MB
    float*    bias = (float*)(Bpl + NTILE * 64 * 64 * 8);
    float*    Yb   = bias + NPAD;                      // 16384*384 fp32

    jcp_repack3<<<384, 256, 0, stream>>>(W_fc, b_fc, W_bin, b_bin, W_res, b_res,
                                         Bph, Bpl, bias);
    jcp_gemm12<<<512, 256, 0, stream>>>(x, Bph, Bpl, bias, Yb);
    jcp_head4<<<BROWS / 16, 256, 0, stream>>>(Yb, out);
}